// Round 5
// baseline (410.898 us; speedup 1.0000x reference)
//
#include <hip/hip_runtime.h>
#include <hip/hip_bf16.h>
#include <cstdint>

// KAN MLP: 256->512->512->256, B=8192, cubic B-splines (uniform grid h=0.25,
// knots -1.75..1.75, 11 bases), BN at the end.
//
// Round-9: rounds 0-4 proved the GEMM is NOT schedule-bound: five different
// schedules all ~60-64 us at MfmaUtil ~31%, and L1 (51.5 GF) == L2 (25.8 GF)
// in time => time tracks A-BYTES, not FLOPs. Root cause: A staged as 64-B
// reads at 12.3-KB row stride (256 scattered granules per block-subtile,
// x256 blocks) -> effective HBM/LLC delivery ~1-2 TB/s. Per-CU arithmetic:
// ~12 KB HBM-missed A per subtile at 3.6 B/cyc = ~3300 cyc = the measured
// 3200-cyc subtile period. MFMA/LDS/VALU all hide in its shadow.
//
// Fix: A is OURS on both sides -> re-tile A in memory to the staging order:
//   A'[p][kb][row 0..255][32 k (64 B)]   (p = M-panel of 256 rows, kb = K/32)
// GEMM stage of one subtile = contiguous 16 KB burst (linear gload_lds16,
// chunk-XOR swizzle applied on the source chunk WITHIN each 64-B line ->
// LDS content bit-identical to round-4's proven core; MFMA paths untouched).
// The expand kernel writes this layout directly: 1 thread per 64-B A-line,
// computing the 3-4 overlapping expand12's for its 32-k window (window
// offset {0,8,4} by kb%3 -- wave-uniform; all indexing static), with the
// 4-way split-K partial sum fused in. Writes perfectly coalesced.
//
// GEMM core kept from round-4 (conflict-free swizzle, reg-dbuf frags,
// 4 LDS slots x 32 KB, stage t+3, counted vmcnt(4), raw s_barrier,
// fp16 split-K partials). Grids: L0 (32,2,4), L1 (32,2,4), L2 (32,1,8)
// = 256 blocks = 1 block/CU.
//
// Workspace (146,800,640 bytes):
//   A'  @ 0          : 8192*6144*2 = 100,663,296 (tiled layout, all layers)
//   W0  @ 100663296  : 3,145,728
//   W1  @ 103809024  : 6,291,456
//   W2  @ 110100480  : 3,145,728
//   P   @ 113246208  : fp16 partials, 33,554,432 (L0/L1: 4 x 8MB; L2: 8 x 4MB)

typedef unsigned short ushort_t;
typedef __bf16 bf16x8 __attribute__((ext_vector_type(8)));
typedef float f32x4 __attribute__((ext_vector_type(4)));
typedef _Float16 f16x4 __attribute__((ext_vector_type(4)));

__device__ __forceinline__ ushort_t f2bf(float f) {
    __bf16 h = (__bf16)f;  // RNE
    return __builtin_bit_cast(ushort_t, h);
}

// async global->LDS 16B copy; LDS dest must be wave-uniform base + lane*16.
__device__ __forceinline__ void gload_lds16(const void* g, void* lds) {
    __builtin_amdgcn_global_load_lds(
        (const __attribute__((address_space(1))) unsigned int*)(uintptr_t)g,
        (__attribute__((address_space(3))) unsigned int*)(unsigned int)(uintptr_t)lds,
        16, 0, 0);
}

// x -> [gelu, b0..b10] (12 bf16). Direct cardinal cubic B-spline:
// basis_j(x) = b(xs - j), xs=(x+1.75)*4;  b(t), a=|t-2|:
//   a<=1: (4-6a^2+3a^3)/6 ; 1<a<2: (2-a)^3/6 ; else 0.
__device__ __forceinline__ void expand12(float x, ushort_t* o) {
    float x3 = x * x * x;
    float y  = 0.7978845608028654f * (x + 0.044715f * x3);
    float e  = __expf(2.0f * y);
    float th = 1.0f - 2.0f / (e + 1.0f);       // tanh(y)
    o[0] = f2bf(0.5f * x * (1.0f + th));
    float xs = (x + 1.75f) * 4.0f;
#pragma unroll
    for (int j = 0; j < 11; ++j) {
        float t  = xs - (float)j;
        float a  = fabsf(t - 2.0f);
        float p1 = (3.0f * a - 6.0f) * a * a + 4.0f;   // a<=1 branch
        float c  = 2.0f - a;
        float p2 = c * c * c;                          // 1<a<2 branch
        float v  = (a <= 1.0f) ? p1 : fmaxf(p2, 0.0f);
        o[1 + j] = f2bf(v * (1.0f / 6.0f));
    }
}

// pack 32 bf16 (from a statically-offset ushort window) into 4 uint4 chunks
__device__ __forceinline__ void pack32(const ushort_t* s, uint4* o) {
#pragma unroll
    for (int c = 0; c < 4; ++c) {
        o[c].x = (unsigned)s[c * 8 + 0] | ((unsigned)s[c * 8 + 1] << 16);
        o[c].y = (unsigned)s[c * 8 + 2] | ((unsigned)s[c * 8 + 3] << 16);
        o[c].z = (unsigned)s[c * 8 + 4] | ((unsigned)s[c * 8 + 5] << 16);
        o[c].w = (unsigned)s[c * 8 + 6] | ((unsigned)s[c * 8 + 7] << 16);
    }
}

// ---------------------------------------------------------------------------
// Tiled expansion: one thread per 64-B A'-line = (p*KB + kb)*256 + row.
// Produces A'[line][k0..k0+31] where k0 = 32*kb, k = 12*i + j.
// Window: i0 = (8*kb)/3, off = k0 - 12*i0 in {0,8,4} by kb%3 (wave-uniform).
// FROMX: h = x (fp32). Else: h = sum of 4 fp16 split-K partials (fused).
// Writes 64 B/thread; consecutive lanes = consecutive lines (coalesced).
// ---------------------------------------------------------------------------
template <int KB, bool FROMX>
__global__ __launch_bounds__(256) void expand_tiled_kernel(
    const float* __restrict__ X, const _Float16* __restrict__ P,
    size_t pstride, ushort_t* __restrict__ A)
{
    constexpr int F = KB * 8 / 3;                 // 96->256, 192->512
    const int idx = blockIdx.x * 256 + threadIdx.x;
    const int row = idx & 255;
    const int pkb = idx >> 8;
    const int kb  = pkb % KB;
    const int p   = pkb / KB;
    const int b   = p * 256 + row;
    const int i0  = (kb * 8) / 3;
    const int cse = kb - 3 * (kb / 3);            // kb % 3

    float h0 = 0.f, h1 = 0.f, h2 = 0.f, h3 = 0.f;
    if (FROMX) {
        const float* xr = X + (size_t)b * F + i0;
        h0 = xr[0]; h1 = xr[1]; h2 = xr[2];
        if (cse == 1) h3 = xr[3];
    } else {
#pragma unroll
        for (int z = 0; z < 4; ++z) {
            const _Float16* pr = P + z * pstride + (size_t)b * F + i0;
            h0 += (float)pr[0]; h1 += (float)pr[1]; h2 += (float)pr[2];
            if (cse == 1) h3 += (float)pr[3];
        }
    }

    ushort_t us[48];
    expand12(h0, us);
    expand12(h1, us + 12);
    expand12(h2, us + 24);
    if (cse == 1) expand12(h3, us + 36);

    uint4 o[4];
    if (cse == 0)      pack32(us + 0, o);   // k0 = 12*i0
    else if (cse == 1) pack32(us + 8, o);   // k0 = 12*i0 + 8
    else               pack32(us + 4, o);   // k0 = 12*i0 + 4

    uint4* dst = (uint4*)(A + (size_t)idx * 32);
    dst[0] = o[0]; dst[1] = o[1]; dst[2] = o[2]; dst[3] = o[3];
}

// ---------------------------------------------------------------------------
// Weight pack (row-major): W[o][i*12+0]=base_w[o][i]; W[o][i*12+1+k]=spline_w.
// ---------------------------------------------------------------------------
__global__ __launch_bounds__(256) void pack_w_kernel(
    const float* __restrict__ bw, const float* __restrict__ sw,
    ushort_t* __restrict__ W, int total)
{
    int idx = blockIdx.x * 256 + threadIdx.x;
    if (idx >= total) return;
    union { ushort_t us[12]; uint2 v[3]; } pk;
    pk.us[0] = f2bf(bw[idx]);
    const float* s = sw + (size_t)idx * 11;
#pragma unroll
    for (int k = 0; k < 11; ++k) pk.us[1 + k] = f2bf(s[k]);
    uint2* dst = (uint2*)(W + (size_t)idx * 12);
    dst[0] = pk.v[0]; dst[1] = pk.v[1]; dst[2] = pk.v[2];
}

// ---------------------------------------------------------------------------
// GEMM: C_z[M,N] = A'[M,kslice] @ W[N,kslice]^T (bf16 in, fp16 out).
// A' is tiled [p][kb][256][32]: subtile stage = contiguous 16 KB burst.
// Tile 256x256, BK=32 subtiles, 512 threads = 8 waves (wm, wn), wave tile
// 128x64 -> acc[8][4]. LDS: 4 slots of {A 256x32 | B 256x32}; rows = 4
// chunks of 16B, LDS(row,c) holds logical chunk c ^ ((row>>1)&3)
// (conflict-free, round-4-verified 0 conflicts).
//   A frag: lane holds A[m=l15][k=q*8+j];  C/D: D[m=q*4+r][n=l15].
// Pipeline per subtile t: stage(t+3) || ds_read frags(t+1) -> ALT regs ||
// 32 MFMA on CUR regs; lgkmcnt(0) (drained under MFMA shadow), vmcnt(4),
// s_barrier. Frag ping-pong via unrolled even/odd bodies (static indexing).
// Split-K over blockIdx.z -> C + z*M*N (fp16).
// ---------------------------------------------------------------------------
#define SLOTE 16384   // elements per LDS slot (32 KB): A 8192 + B 8192

__global__ __launch_bounds__(512, 2) void gemm_kernel(
    const ushort_t* __restrict__ A,  // tiled [p][KBT][256][32]
    const ushort_t* __restrict__ W,  // N x K row-major
    _Float16* __restrict__ C,        // split-K partials (fp16), z*M*N apart
    int M, int N, int KBT, int scps) // KBT = K/32; scps even, >= 4
{
    extern __shared__ __align__(16) ushort_t lds[];   // 4*SLOTE = 128 KB

    const int t   = threadIdx.x;
    const int l   = t & 63;
    const int w   = t >> 6;        // 0..7
    const int wm  = w >> 2;        // 0..1  (M half)
    const int wn  = w & 3;         // 0..3  (N quarter)
    const int l15 = l & 15;
    const int q   = l >> 4;        // 0..3
    const int K   = KBT << 5;
    const int blockN = blockIdx.y * 256;
    const int kb0 = blockIdx.z * scps;
    const int nt  = scps;
    _Float16* Cz = C + (size_t)blockIdx.z * M * N;

    const ushort_t* Apan = A + (size_t)blockIdx.x * KBT * 8192;
    const ushort_t* Wb   = W + (size_t)blockN * K;

    // stage one 32-k subtile: A = contiguous 16 KB (tiled layout); B = 256
    // rows x 64 B strided. Source chunk XOR'd within each 64-B line so LDS
    // (row,c) holds logical chunk c ^ ((row>>1)&3); dest linear (required).
    auto stage = [&](int kb, int slot) {
        ushort_t* da = lds + slot * SLOTE;
        ushort_t* db = da + 8192;
        const ushort_t* sa = Apan + (size_t)kb * 8192;
#pragma unroll
        for (int it = 0; it < 2; ++it) {
            int s = it * 512 + t;
            int row = s >> 2, g = (s & 3) ^ ((row >> 1) & 3);
            gload_lds16(sa + (row << 5) + (g << 3), da + s * 8);
        }
#pragma unroll
        for (int it = 0; it < 2; ++it) {
            int s = it * 512 + t;
            int row = s >> 2, g = (s & 3) ^ ((row >> 1) & 3);
            gload_lds16(Wb + ((size_t)row * K + (kb << 5) + (g << 3)), db + s * 8);
        }
    };

    // 12 ds_read_b128 of one subtile's fragments into the given reg arrays.
    auto ldfrags = [&](int slot, bf16x8* afr, bf16x8* bfr) {
        const ushort_t* Ac = lds + slot * SLOTE;
        const ushort_t* Bc = Ac + 8192;
#pragma unroll
        for (int ni = 0; ni < 4; ++ni) {
            int n = wn * 64 + ni * 16 + l15;
            bfr[ni] = *(const bf16x8*)&Bc[(size_t)((n << 2) + (q ^ ((n >> 1) & 3))) * 8];
        }
#pragma unroll
        for (int mi = 0; mi < 8; ++mi) {
            int m = wm * 128 + mi * 16 + l15;
            afr[mi] = *(const bf16x8*)&Ac[(size_t)((m << 2) + (q ^ ((m >> 1) & 3))) * 8];
        }
    };

    f32x4 acc[8][4];
#pragma unroll
    for (int i = 0; i < 8; ++i)
#pragma unroll
        for (int j = 0; j < 4; ++j) acc[i][j] = (f32x4){0.f, 0.f, 0.f, 0.f};

    // prologue: stage 0,1,2; ensure 0 AND 1 resident (frags(1) read at tt=0).
    stage(kb0 + 0, 0); stage(kb0 + 1, 1); stage(kb0 + 2, 2);
    asm volatile("s_waitcnt vmcnt(4)" ::: "memory");
    __builtin_amdgcn_s_barrier();

    bf16x8 aA[8], bA[4], aB[8], bB[4];
    ldfrags(0, aA, bA);
    asm volatile("s_waitcnt lgkmcnt(0)" ::: "memory");

    // per-subtile body: compute on (ac,bc)=frags(tt); prefetch frags(tt+1)
    // into (an,bn); stage subtile tt+3.
    auto body = [&](int tt, bf16x8* ac, bf16x8* bc, bf16x8* an, bf16x8* bn) {
        if (tt + 3 < nt) stage(kb0 + tt + 3, (tt + 3) & 3);
        if (tt + 1 < nt) ldfrags((tt + 1) & 3, an, bn);
        __builtin_amdgcn_sched_barrier(0);   // pin loads/reads before MFMAs
        __builtin_amdgcn_s_setprio(1);
#pragma unroll
        for (int mi = 0; mi < 8; ++mi)
#pragma unroll
            for (int ni = 0; ni < 4; ++ni)
                acc[mi][ni] = __builtin_amdgcn_mfma_f32_16x16x32_bf16(
                    ac[mi], bc[ni], acc[mi][ni], 0, 0, 0);
        __builtin_amdgcn_s_setprio(0);
        // alt-frag reads drained under the MFMA shadow -> near-free wait.
        asm volatile("s_waitcnt lgkmcnt(0)" ::: "memory");
        // subtile tt+2 resident for next iter's prefetch; tt+3 in flight.
        if (tt + 3 < nt)      asm volatile("s_waitcnt vmcnt(4)" ::: "memory");
        else if (tt + 2 < nt) asm volatile("s_waitcnt vmcnt(0)" ::: "memory");
        __builtin_amdgcn_s_barrier();
    };

    for (int tt = 0; tt < nt; tt += 2) {
        body(tt,     aA, bA, aB, bB);
        body(tt + 1, aB, bB, aA, bA);
    }

    const int blockM = blockIdx.x * 256;
    // epilogue: fp16 stores into this split's partial buffer
#pragma unroll
    for (int ni = 0; ni < 4; ++ni) {
        int n = blockN + wn * 64 + ni * 16 + l15;
#pragma unroll
        for (int mi = 0; mi < 8; ++mi) {
            int mb = blockM + wm * 128 + mi * 16 + q * 4;
#pragma unroll
            for (int r = 0; r < 4; ++r)
                Cz[(size_t)(mb + r) * N + n] = (_Float16)acc[mi][ni][r];
        }
    }
}

// ---------------------------------------------------------------------------
// Final: out = gamma*rsqrt(var+eps)*(sum of 8 fp16 partials - mean) + beta.
// ---------------------------------------------------------------------------
__global__ __launch_bounds__(256) void bn_reduce_kernel(
    const _Float16* __restrict__ Q, size_t qstride,
    const float* __restrict__ gamma, const float* __restrict__ beta,
    const float* __restrict__ mean,  const float* __restrict__ var,
    float4* __restrict__ out, int n4)
{
    int i = blockIdx.x * 256 + threadIdx.x;
    if (i >= n4) return;
    float sx = 0.f, sy = 0.f, sz = 0.f, sw = 0.f;
#pragma unroll
    for (int s = 0; s < 8; ++s) {
        f16x4 v = *(const f16x4*)(Q + s * qstride + 4 * (size_t)i);
        sx += (float)v.x; sy += (float)v.y; sz += (float)v.z; sw += (float)v.w;
    }
    int nb = (i * 4) & 255;
    float4 g  = *(const float4*)(gamma + nb);
    float4 be = *(const float4*)(beta + nb);
    float4 mn = *(const float4*)(mean + nb);
    float4 vr = *(const float4*)(var + nb);
    float4 o;
    o.x = g.x * rsqrtf(vr.x + 1e-5f) * (sx - mn.x) + be.x;
    o.y = g.y * rsqrtf(vr.y + 1e-5f) * (sy - mn.y) + be.y;
    o.z = g.z * rsqrtf(vr.z + 1e-5f) * (sz - mn.z) + be.z;
    o.w = g.w * rsqrtf(vr.w + 1e-5f) * (sw - mn.w) + be.w;
    out[i] = o;
}

// ---------------------------------------------------------------------------
extern "C" void kernel_launch(void* const* d_in, const int* in_sizes, int n_in,
                              void* d_out, int out_size, void* d_ws, size_t ws_size,
                              hipStream_t stream) {
    const float* x     = (const float*)d_in[0];
    const float* bw0   = (const float*)d_in[2];
    const float* sw0   = (const float*)d_in[3];
    const float* bw1   = (const float*)d_in[5];
    const float* sw1   = (const float*)d_in[6];
    const float* bw2   = (const float*)d_in[8];
    const float* sw2   = (const float*)d_in[9];
    const float* gamma = (const float*)d_in[10];
    const float* beta  = (const float*)d_in[11];
    const float* mean  = (const float*)d_in[12];
    const float* var   = (const float*)d_in[13];

    char* ws = (char*)d_ws;
    ushort_t*  Abuf = (ushort_t*)(ws);
    ushort_t*  W0   = (ushort_t*)(ws + 100663296);
    ushort_t*  W1   = (ushort_t*)(ws + 103809024);
    ushort_t*  W2   = (ushort_t*)(ws + 110100480);
    _Float16*  P    = (_Float16*)(ws + 113246208);   // 32 MB fp16 partials
    float*     out  = (float*)d_out;

    const size_t PS01 = (size_t)8192 * 512;   // L0/L1 partial stride (elems)
    const size_t PS2  = (size_t)8192 * 256;   // L2 partial stride (elems)
    const size_t GEMM_LDS = 4 * SLOTE * sizeof(ushort_t);  // 131072 B

    // weight packing (d_ws re-poisoned every call -> repack)
    pack_w_kernel<<<(512 * 256 + 255) / 256, 256, 0, stream>>>(bw0, sw0, W0, 512 * 256);
    pack_w_kernel<<<(512 * 512 + 255) / 256, 256, 0, stream>>>(bw1, sw1, W1, 512 * 512);
    pack_w_kernel<<<(256 * 512 + 255) / 256, 256, 0, stream>>>(bw2, sw2, W2, 256 * 512);

    // layer 0: K=3072 (KB=96), N=512, SK=4 (scps=24)
    expand_tiled_kernel<96, true><<<32 * 96, 256, 0, stream>>>(x, nullptr, 0, Abuf);
    {
        dim3 g(32, 2, 4);
        gemm_kernel<<<g, 512, GEMM_LDS, stream>>>(Abuf, W0, P, 8192, 512, 96, 24);
    }
    // layer 1: K=6144 (KB=192), N=512, SK=4 (scps=48); expand sums L0 partials
    expand_tiled_kernel<192, false><<<32 * 192, 256, 0, stream>>>(nullptr, P, PS01, Abuf);
    {
        dim3 g(32, 2, 4);
        gemm_kernel<<<g, 512, GEMM_LDS, stream>>>(Abuf, W1, P, 8192, 512, 192, 48);
    }
    // layer 2: K=6144 (KB=192), N=256, SK=8 (scps=24); expand sums L1 partials
    expand_tiled_kernel<192, false><<<32 * 192, 256, 0, stream>>>(nullptr, P, PS01, Abuf);
    {
        dim3 g(32, 1, 8);
        gemm_kernel<<<g, 512, GEMM_LDS, stream>>>(Abuf, W2, P, 8192, 256, 192, 24);
    }
    // BN + 8-way split-K reduce -> out
    bn_reduce_kernel<<<2048, 256, 0, stream>>>(
        P, PS2, gamma, beta, mean, var, (float4*)out, 8192 * 256 / 4);
}

// Round 6
// 342.064 us; speedup vs baseline: 1.2012x; 1.2012x over previous
//
#include <hip/hip_runtime.h>
#include <hip/hip_bf16.h>
#include <cstdint>

// KAN MLP: 256->512->512->256, B=8192, cubic B-splines (uniform grid h=0.25,
// knots -1.75..1.75, 11 bases), BN at the end.
//
// Round-10: round-9's A' retile moved the GEMM bottleneck (gemms dropped out
// of top-5; implied ~75 us combined gain) but the thread-per-line expand
// read P in 6-8 B granules at 1 KB stride -> FETCH 200 MB (6x amplification)
// and 83 us per expand. This round rewrites ONLY the expand:
//   thread = (b row, 32-col input group). 32 cols -> k-range 384 = exactly
//   12 whole A' subtile lines (LCM(12,32)=96 | 384): no fractional windows,
//   each input expanded exactly once.
//   - reads: 32 contiguous values (X: 2x64B; P: 4 buffers x 64 B vector
//     loads) -> full-line granules, no fetch amplification
//   - writes: 12 x 64-B lines; lanes = consecutive b -> wave writes 4 KB
//     contiguous per line index. Output layout byte-identical to round-9
//     (GEMM untouched, still verified).
// GEMM kept from round-9: A' tiled [p][kb][256][32] = contiguous 16 KB
// subtile bursts, conflict-free chunk-XOR swizzle, reg-dbuf frags, 4 LDS
// slots, stage t+3, counted vmcnt(4), raw s_barrier, fp16 split-K partials.
// Grids: L0 (32,2,4), L1 (32,2,4), L2 (32,1,8) = 256 blocks = 1 block/CU.
//
// Workspace (146,800,640 bytes):
//   A'  @ 0          : 8192*6144*2 = 100,663,296 (tiled layout, all layers)
//   W0  @ 100663296  : 3,145,728
//   W1  @ 103809024  : 6,291,456
//   W2  @ 110100480  : 3,145,728
//   P   @ 113246208  : fp16 partials, 33,554,432 (L0/L1: 4 x 8MB; L2: 8 x 4MB)

typedef unsigned short ushort_t;
typedef __bf16 bf16x8 __attribute__((ext_vector_type(8)));
typedef float f32x4 __attribute__((ext_vector_type(4)));
typedef _Float16 f16x4 __attribute__((ext_vector_type(4)));
typedef _Float16 f16x8 __attribute__((ext_vector_type(8)));

__device__ __forceinline__ ushort_t f2bf(float f) {
    __bf16 h = (__bf16)f;  // RNE
    return __builtin_bit_cast(ushort_t, h);
}

// async global->LDS 16B copy; LDS dest must be wave-uniform base + lane*16.
__device__ __forceinline__ void gload_lds16(const void* g, void* lds) {
    __builtin_amdgcn_global_load_lds(
        (const __attribute__((address_space(1))) unsigned int*)(uintptr_t)g,
        (__attribute__((address_space(3))) unsigned int*)(unsigned int)(uintptr_t)lds,
        16, 0, 0);
}

// x -> [gelu, b0..b10] (12 bf16). Direct cardinal cubic B-spline:
// basis_j(x) = b(xs - j), xs=(x+1.75)*4;  b(t), a=|t-2|:
//   a<=1: (4-6a^2+3a^3)/6 ; 1<a<2: (2-a)^3/6 ; else 0.
__device__ __forceinline__ void expand12(float x, ushort_t* o) {
    float x3 = x * x * x;
    float y  = 0.7978845608028654f * (x + 0.044715f * x3);
    float e  = __expf(2.0f * y);
    float th = 1.0f - 2.0f / (e + 1.0f);       // tanh(y)
    o[0] = f2bf(0.5f * x * (1.0f + th));
    float xs = (x + 1.75f) * 4.0f;
#pragma unroll
    for (int j = 0; j < 11; ++j) {
        float t  = xs - (float)j;
        float a  = fabsf(t - 2.0f);
        float p1 = (3.0f * a - 6.0f) * a * a + 4.0f;   // a<=1 branch
        float c  = 2.0f - a;
        float p2 = c * c * c;                          // 1<a<2 branch
        float v  = (a <= 1.0f) ? p1 : fmaxf(p2, 0.0f);
        o[1 + j] = f2bf(v * (1.0f / 6.0f));
    }
}

// pack 32 bf16 (from a statically-offset ushort window) into 4 uint4 chunks
__device__ __forceinline__ void pack32(const ushort_t* s, uint4* o) {
#pragma unroll
    for (int c = 0; c < 4; ++c) {
        o[c].x = (unsigned)s[c * 8 + 0] | ((unsigned)s[c * 8 + 1] << 16);
        o[c].y = (unsigned)s[c * 8 + 2] | ((unsigned)s[c * 8 + 3] << 16);
        o[c].z = (unsigned)s[c * 8 + 4] | ((unsigned)s[c * 8 + 5] << 16);
        o[c].w = (unsigned)s[c * 8 + 6] | ((unsigned)s[c * 8 + 7] << 16);
    }
}

// ---------------------------------------------------------------------------
// Tiled expansion, granule-clean: thread = (b, cg) with idx = cg*8192 + b.
// Reads input cols [32cg, 32cg+32) of row b CONTIGUOUSLY (X fp32 or sum of
// 4 fp16 partials), expands each col once, writes the 12 whole A'-lines
// (subtiles kb = 12cg .. 12cg+11) of row b: 12 x 64 B contiguous stores,
// lanes = consecutive b -> coalesced 4-KB wave spans.
// ---------------------------------------------------------------------------
template <int KB, bool FROMX>
__global__ __launch_bounds__(256) void expand_tiled_kernel(
    const float* __restrict__ X, const _Float16* __restrict__ P,
    size_t pstride, ushort_t* __restrict__ A)
{
    constexpr int F = KB * 8 / 3;                 // 96->256, 192->512
    const int idx = blockIdx.x * 256 + threadIdx.x;
    const int b   = idx & 8191;
    const int cg  = idx >> 13;                    // 0..F/32-1
    const int row = b & 255;
    const int p   = b >> 8;

    float h[32];
    if (FROMX) {
        const float4* xr = (const float4*)(X + (size_t)b * F + cg * 32);
#pragma unroll
        for (int v = 0; v < 8; ++v) {
            float4 f = xr[v];
            h[4 * v + 0] = f.x; h[4 * v + 1] = f.y;
            h[4 * v + 2] = f.z; h[4 * v + 3] = f.w;
        }
    } else {
#pragma unroll
        for (int u = 0; u < 32; ++u) h[u] = 0.f;
#pragma unroll
        for (int z = 0; z < 4; ++z) {
            const f16x8* pr = (const f16x8*)(P + z * pstride + (size_t)b * F + cg * 32);
#pragma unroll
            for (int v = 0; v < 4; ++v) {
                f16x8 a = pr[v];
#pragma unroll
                for (int e = 0; e < 8; ++e) h[8 * v + e] += (float)a[e];
            }
        }
    }

    const size_t lbase = ((size_t)p * KB + 12 * cg) * 256 + row;
#pragma unroll
    for (int ci8 = 0; ci8 < 4; ++ci8) {
        ushort_t us[96];
#pragma unroll
        for (int u = 0; u < 8; ++u) expand12(h[ci8 * 8 + u], us + 12 * u);
#pragma unroll
        for (int kk = 0; kk < 3; ++kk) {
            uint4 o[4];
            pack32(us + 32 * kk, o);
            uint4* dst = (uint4*)(A + (lbase + (size_t)(3 * ci8 + kk) * 256) * 32);
            dst[0] = o[0]; dst[1] = o[1]; dst[2] = o[2]; dst[3] = o[3];
        }
    }
}

// ---------------------------------------------------------------------------
// Weight pack (row-major): W[o][i*12+0]=base_w[o][i]; W[o][i*12+1+k]=spline_w.
// ---------------------------------------------------------------------------
__global__ __launch_bounds__(256) void pack_w_kernel(
    const float* __restrict__ bw, const float* __restrict__ sw,
    ushort_t* __restrict__ W, int total)
{
    int idx = blockIdx.x * 256 + threadIdx.x;
    if (idx >= total) return;
    union { ushort_t us[12]; uint2 v[3]; } pk;
    pk.us[0] = f2bf(bw[idx]);
    const float* s = sw + (size_t)idx * 11;
#pragma unroll
    for (int k = 0; k < 11; ++k) pk.us[1 + k] = f2bf(s[k]);
    uint2* dst = (uint2*)(W + (size_t)idx * 12);
    dst[0] = pk.v[0]; dst[1] = pk.v[1]; dst[2] = pk.v[2];
}

// ---------------------------------------------------------------------------
// GEMM: C_z[M,N] = A'[M,kslice] @ W[N,kslice]^T (bf16 in, fp16 out).
// A' is tiled [p][kb][256][32]: subtile stage = contiguous 16 KB burst.
// Tile 256x256, BK=32 subtiles, 512 threads = 8 waves (wm, wn), wave tile
// 128x64 -> acc[8][4]. LDS: 4 slots of {A 256x32 | B 256x32}; rows = 4
// chunks of 16B, LDS(row,c) holds logical chunk c ^ ((row>>1)&3)
// (conflict-free, round-4-verified 0 conflicts).
//   A frag: lane holds A[m=l15][k=q*8+j];  C/D: D[m=q*4+r][n=l15].
// Pipeline per subtile t: stage(t+3) || ds_read frags(t+1) -> ALT regs ||
// 32 MFMA on CUR regs; lgkmcnt(0) (drained under MFMA shadow), vmcnt(4),
// s_barrier. Frag ping-pong via unrolled even/odd bodies (static indexing).
// Split-K over blockIdx.z -> C + z*M*N (fp16).
// ---------------------------------------------------------------------------
#define SLOTE 16384   // elements per LDS slot (32 KB): A 8192 + B 8192

__global__ __launch_bounds__(512, 2) void gemm_kernel(
    const ushort_t* __restrict__ A,  // tiled [p][KBT][256][32]
    const ushort_t* __restrict__ W,  // N x K row-major
    _Float16* __restrict__ C,        // split-K partials (fp16), z*M*N apart
    int M, int N, int KBT, int scps) // KBT = K/32; scps even, >= 4
{
    extern __shared__ __align__(16) ushort_t lds[];   // 4*SLOTE = 128 KB

    const int t   = threadIdx.x;
    const int l   = t & 63;
    const int w   = t >> 6;        // 0..7
    const int wm  = w >> 2;        // 0..1  (M half)
    const int wn  = w & 3;         // 0..3  (N quarter)
    const int l15 = l & 15;
    const int q   = l >> 4;        // 0..3
    const int K   = KBT << 5;
    const int blockN = blockIdx.y * 256;
    const int kb0 = blockIdx.z * scps;
    const int nt  = scps;
    _Float16* Cz = C + (size_t)blockIdx.z * M * N;

    const ushort_t* Apan = A + (size_t)blockIdx.x * KBT * 8192;
    const ushort_t* Wb   = W + (size_t)blockN * K;

    // stage one 32-k subtile: A = contiguous 16 KB (tiled layout); B = 256
    // rows x 64 B strided. Source chunk XOR'd within each 64-B line so LDS
    // (row,c) holds logical chunk c ^ ((row>>1)&3); dest linear (required).
    auto stage = [&](int kb, int slot) {
        ushort_t* da = lds + slot * SLOTE;
        ushort_t* db = da + 8192;
        const ushort_t* sa = Apan + (size_t)kb * 8192;
#pragma unroll
        for (int it = 0; it < 2; ++it) {
            int s = it * 512 + t;
            int row = s >> 2, g = (s & 3) ^ ((row >> 1) & 3);
            gload_lds16(sa + (row << 5) + (g << 3), da + s * 8);
        }
#pragma unroll
        for (int it = 0; it < 2; ++it) {
            int s = it * 512 + t;
            int row = s >> 2, g = (s & 3) ^ ((row >> 1) & 3);
            gload_lds16(Wb + ((size_t)row * K + (kb << 5) + (g << 3)), db + s * 8);
        }
    };

    // 12 ds_read_b128 of one subtile's fragments into the given reg arrays.
    auto ldfrags = [&](int slot, bf16x8* afr, bf16x8* bfr) {
        const ushort_t* Ac = lds + slot * SLOTE;
        const ushort_t* Bc = Ac + 8192;
#pragma unroll
        for (int ni = 0; ni < 4; ++ni) {
            int n = wn * 64 + ni * 16 + l15;
            bfr[ni] = *(const bf16x8*)&Bc[(size_t)((n << 2) + (q ^ ((n >> 1) & 3))) * 8];
        }
#pragma unroll
        for (int mi = 0; mi < 8; ++mi) {
            int m = wm * 128 + mi * 16 + l15;
            afr[mi] = *(const bf16x8*)&Ac[(size_t)((m << 2) + (q ^ ((m >> 1) & 3))) * 8];
        }
    };

    f32x4 acc[8][4];
#pragma unroll
    for (int i = 0; i < 8; ++i)
#pragma unroll
        for (int j = 0; j < 4; ++j) acc[i][j] = (f32x4){0.f, 0.f, 0.f, 0.f};

    // prologue: stage 0,1,2; ensure 0 AND 1 resident (frags(1) read at tt=0).
    stage(kb0 + 0, 0); stage(kb0 + 1, 1); stage(kb0 + 2, 2);
    asm volatile("s_waitcnt vmcnt(4)" ::: "memory");
    __builtin_amdgcn_s_barrier();

    bf16x8 aA[8], bA[4], aB[8], bB[4];
    ldfrags(0, aA, bA);
    asm volatile("s_waitcnt lgkmcnt(0)" ::: "memory");

    // per-subtile body: compute on (ac,bc)=frags(tt); prefetch frags(tt+1)
    // into (an,bn); stage subtile tt+3.
    auto body = [&](int tt, bf16x8* ac, bf16x8* bc, bf16x8* an, bf16x8* bn) {
        if (tt + 3 < nt) stage(kb0 + tt + 3, (tt + 3) & 3);
        if (tt + 1 < nt) ldfrags((tt + 1) & 3, an, bn);
        __builtin_amdgcn_sched_barrier(0);   // pin loads/reads before MFMAs
        __builtin_amdgcn_s_setprio(1);
#pragma unroll
        for (int mi = 0; mi < 8; ++mi)
#pragma unroll
            for (int ni = 0; ni < 4; ++ni)
                acc[mi][ni] = __builtin_amdgcn_mfma_f32_16x16x32_bf16(
                    ac[mi], bc[ni], acc[mi][ni], 0, 0, 0);
        __builtin_amdgcn_s_setprio(0);
        // alt-frag reads drained under the MFMA shadow -> near-free wait.
        asm volatile("s_waitcnt lgkmcnt(0)" ::: "memory");
        // subtile tt+2 resident for next iter's prefetch; tt+3 in flight.
        if (tt + 3 < nt)      asm volatile("s_waitcnt vmcnt(4)" ::: "memory");
        else if (tt + 2 < nt) asm volatile("s_waitcnt vmcnt(0)" ::: "memory");
        __builtin_amdgcn_s_barrier();
    };

    for (int tt = 0; tt < nt; tt += 2) {
        body(tt,     aA, bA, aB, bB);
        body(tt + 1, aB, bB, aA, bA);
    }

    const int blockM = blockIdx.x * 256;
    // epilogue: fp16 stores into this split's partial buffer
#pragma unroll
    for (int ni = 0; ni < 4; ++ni) {
        int n = blockN + wn * 64 + ni * 16 + l15;
#pragma unroll
        for (int mi = 0; mi < 8; ++mi) {
            int mb = blockM + wm * 128 + mi * 16 + q * 4;
#pragma unroll
            for (int r = 0; r < 4; ++r)
                Cz[(size_t)(mb + r) * N + n] = (_Float16)acc[mi][ni][r];
        }
    }
}

// ---------------------------------------------------------------------------
// Final: out = gamma*rsqrt(var+eps)*(sum of 8 fp16 partials - mean) + beta.
// ---------------------------------------------------------------------------
__global__ __launch_bounds__(256) void bn_reduce_kernel(
    const _Float16* __restrict__ Q, size_t qstride,
    const float* __restrict__ gamma, const float* __restrict__ beta,
    const float* __restrict__ mean,  const float* __restrict__ var,
    float4* __restrict__ out, int n4)
{
    int i = blockIdx.x * 256 + threadIdx.x;
    if (i >= n4) return;
    float sx = 0.f, sy = 0.f, sz = 0.f, sw = 0.f;
#pragma unroll
    for (int s = 0; s < 8; ++s) {
        f16x4 v = *(const f16x4*)(Q + s * qstride + 4 * (size_t)i);
        sx += (float)v.x; sy += (float)v.y; sz += (float)v.z; sw += (float)v.w;
    }
    int nb = (i * 4) & 255;
    float4 g  = *(const float4*)(gamma + nb);
    float4 be = *(const float4*)(beta + nb);
    float4 mn = *(const float4*)(mean + nb);
    float4 vr = *(const float4*)(var + nb);
    float4 o;
    o.x = g.x * rsqrtf(vr.x + 1e-5f) * (sx - mn.x) + be.x;
    o.y = g.y * rsqrtf(vr.y + 1e-5f) * (sy - mn.y) + be.y;
    o.z = g.z * rsqrtf(vr.z + 1e-5f) * (sz - mn.z) + be.z;
    o.w = g.w * rsqrtf(vr.w + 1e-5f) * (sw - mn.w) + be.w;
    out[i] = o;
}

// ---------------------------------------------------------------------------
extern "C" void kernel_launch(void* const* d_in, const int* in_sizes, int n_in,
                              void* d_out, int out_size, void* d_ws, size_t ws_size,
                              hipStream_t stream) {
    const float* x     = (const float*)d_in[0];
    const float* bw0   = (const float*)d_in[2];
    const float* sw0   = (const float*)d_in[3];
    const float* bw1   = (const float*)d_in[5];
    const float* sw1   = (const float*)d_in[6];
    const float* bw2   = (const float*)d_in[8];
    const float* sw2   = (const float*)d_in[9];
    const float* gamma = (const float*)d_in[10];
    const float* beta  = (const float*)d_in[11];
    const float* mean  = (const float*)d_in[12];
    const float* var   = (const float*)d_in[13];

    char* ws = (char*)d_ws;
    ushort_t*  Abuf = (ushort_t*)(ws);
    ushort_t*  W0   = (ushort_t*)(ws + 100663296);
    ushort_t*  W1   = (ushort_t*)(ws + 103809024);
    ushort_t*  W2   = (ushort_t*)(ws + 110100480);
    _Float16*  P    = (_Float16*)(ws + 113246208);   // 32 MB fp16 partials
    float*     out  = (float*)d_out;

    const size_t PS01 = (size_t)8192 * 512;   // L0/L1 partial stride (elems)
    const size_t PS2  = (size_t)8192 * 256;   // L2 partial stride (elems)
    const size_t GEMM_LDS = 4 * SLOTE * sizeof(ushort_t);  // 131072 B

    // weight packing (d_ws re-poisoned every call -> repack)
    pack_w_kernel<<<(512 * 256 + 255) / 256, 256, 0, stream>>>(bw0, sw0, W0, 512 * 256);
    pack_w_kernel<<<(512 * 512 + 255) / 256, 256, 0, stream>>>(bw1, sw1, W1, 512 * 512);
    pack_w_kernel<<<(256 * 512 + 255) / 256, 256, 0, stream>>>(bw2, sw2, W2, 256 * 512);

    // layer 0: K=3072 (KB=96), F=256 -> 8 col-groups x 8192 rows = 256 blocks
    expand_tiled_kernel<96, true><<<256, 256, 0, stream>>>(x, nullptr, 0, Abuf);
    {
        dim3 g(32, 2, 4);
        gemm_kernel<<<g, 512, GEMM_LDS, stream>>>(Abuf, W0, P, 8192, 512, 96, 24);
    }
    // layer 1: K=6144 (KB=192), F=512 -> 16 col-groups x 8192 = 512 blocks
    expand_tiled_kernel<192, false><<<512, 256, 0, stream>>>(nullptr, P, PS01, Abuf);
    {
        dim3 g(32, 2, 4);
        gemm_kernel<<<g, 512, GEMM_LDS, stream>>>(Abuf, W1, P, 8192, 512, 192, 48);
    }
    // layer 2: K=6144 (KB=192), F=512 -> 512 blocks; SK=8
    expand_tiled_kernel<192, false><<<512, 256, 0, stream>>>(nullptr, P, PS01, Abuf);
    {
        dim3 g(32, 1, 8);
        gemm_kernel<<<g, 512, GEMM_LDS, stream>>>(Abuf, W2, P, 8192, 256, 192, 24);
    }
    // BN + 8-way split-K reduce -> out
    bn_reduce_kernel<<<2048, 256, 0, stream>>>(
        P, PS2, gamma, beta, mean, var, (float4*)out, 8192 * 256 / 4);
}